// Round 17
// baseline (267.341 us; speedup 1.0000x reference)
//
#include <hip/hip_runtime.h>
#include <hip/hip_bf16.h>

#define G 5
#define B 8
#define CIN 320
#define CIN_G 64
#define COUT 480
#define COUT_G 96
#define NPOS 15872
#define NSTAT (B*NPOS)
#define BN_EPS 1e-5f
#define KDIM 62

typedef float  f32x4 __attribute__((ext_vector_type(4)));
typedef float  f32x2 __attribute__((ext_vector_type(2)));
typedef __bf16 bf16x8 __attribute__((ext_vector_type(8)));
typedef __bf16 bf16x4 __attribute__((ext_vector_type(4)));

// ---------------- prep: W1,W2 -> bf16; Ltb[g][p][64k] = L[g][k][p] bf16 zero-padded;
//                  L column sums (stride-64 padded)
__global__ __launch_bounds__(256) void k_prep(
    const float* __restrict__ W1, const float* __restrict__ W2, const float* __restrict__ L,
    __bf16* __restrict__ W1b, __bf16* __restrict__ W2b, __bf16* __restrict__ Ltb,
    float* __restrict__ lcs)
{
    const int bx = blockIdx.x;
    if (bx < 300) {
        const int i = bx * 256 + threadIdx.x;
        if (i < 30720) W1b[i] = (__bf16)W1[i];
        else W2b[i - 30720] = (__bf16)W2[i - 30720];
    } else {
        const int g = bx - 300;
        for (int e = threadIdx.x; e < 4096; e += 256) {
            const int p = e >> 6, k = e & 63;
            Ltb[g * 4096 + e] = (__bf16)((p < KDIM && k < KDIM) ? L[(g * KDIM + k) * KDIM + p] : 0.f);
        }
        if (threadIdx.x < 64) {
            float s = 0.f;
            if (threadIdx.x < KDIM)
                for (int k = 0; k < KDIM; ++k) s += L[(g * KDIM + k) * KDIM + threadIdx.x];
            lcs[g * 64 + threadIdx.x] = s;
        }
    }
}

// ---------------- BN1 stats pass: conv1 to REGISTERS only, reduce stats (R11-verified)
__global__ __launch_bounds__(256) void k_stat1(
    const float* __restrict__ x, const __bf16* __restrict__ W1b,
    float* __restrict__ sum1, float* __restrict__ sq1)
{
    __shared__ __bf16 wl[COUT_G * 72];            // 13824 B
    __shared__ float st[COUT_G * 2];
    const int b = blockIdx.z, g = blockIdx.y;
    for (int i = threadIdx.x; i < 768; i += 256) {
        const int idx = i * 8, o = idx >> 6, c = idx & 63;
        *(bf16x8*)&wl[o * 72 + c] = *(const bf16x8*)&W1b[g * 6144 + idx];
    }
    if (threadIdx.x < COUT_G * 2) st[threadIdx.x] = 0.f;
    __syncthreads();

    const int wid = threadIdx.x >> 6, lane = threadIdx.x & 63;
    const int lg = lane >> 4, lr = lane & 15;
    const int jw = blockIdx.x * 4 + wid;
    const float* xb = x + ((size_t)b * CIN + g * CIN_G) * NPOS;

    f32x4 acc1[6][4];
#pragma unroll
    for (int mt = 0; mt < 6; ++mt)
#pragma unroll
        for (int nt = 0; nt < 4; ++nt) acc1[mt][nt] = (f32x4){0.f,0.f,0.f,0.f};

#pragma unroll
    for (int ks = 0; ks < 2; ++ks) {
        const int c0 = ks * 32 + lg * 8;
        bf16x8 af[6];
#pragma unroll
        for (int mt = 0; mt < 6; ++mt)
            af[mt] = *(const bf16x8*)&wl[(mt * 16 + lr) * 72 + c0];
#pragma unroll
        for (int nt = 0; nt < 4; ++nt) {
            const int kcol = nt * 16 + lr;
            bf16x8 bfv;
            if (kcol < KDIM) {
                const float* xp = xb + jw * KDIM + kcol;
#pragma unroll
                for (int i = 0; i < 8; ++i) bfv[i] = (__bf16)xp[(size_t)(c0 + i) * NPOS];
            } else {
#pragma unroll
                for (int i = 0; i < 8; ++i) bfv[i] = (__bf16)0.f;
            }
#pragma unroll
            for (int mt = 0; mt < 6; ++mt)
                acc1[mt][nt] = __builtin_amdgcn_mfma_f32_16x16x32_bf16(af[mt], bfv, acc1[mt][nt], 0, 0, 0);
        }
    }

#pragma unroll
    for (int mt = 0; mt < 6; ++mt) {
#pragma unroll
        for (int r = 0; r < 4; ++r) {
            float s = 0.f, q = 0.f;
#pragma unroll
            for (int nt = 0; nt < 4; ++nt) {
                const float v = acc1[mt][nt][r];
                s += v; q += v * v;
            }
#pragma unroll
            for (int m = 1; m <= 8; m <<= 1) {
                s += __shfl_xor(s, m);
                q += __shfl_xor(q, m);
            }
            if (lr == 0) {
                atomicAdd(&st[(mt * 16 + lg * 4 + r) * 2], s);
                atomicAdd(&st[(mt * 16 + lg * 4 + r) * 2 + 1], q);
            }
        }
    }
    __syncthreads();
    if (threadIdx.x < COUT_G) {
        atomicAdd(&sum1[g * COUT_G + threadIdx.x], st[threadIdx.x * 2]);
        atomicAdd(&sq1[g * COUT_G + threadIdx.x], st[threadIdx.x * 2 + 1]);
    }
}

// ---------------- BN coefs (shared by BN1 and BN2)
__global__ void k_fin(const float* __restrict__ sum, const float* __restrict__ sq,
                      const float* __restrict__ gamma, const float* __restrict__ beta,
                      float* __restrict__ a, float* __restrict__ bb)
{
    const int ch = blockIdx.x * blockDim.x + threadIdx.x;
    if (ch < COUT) {
        const float invN = 1.f / (float)NSTAT;
        const float mean = sum[ch] * invN;
        const float var  = sq[ch] * invN - mean * mean;
        const float rstd = rsqrtf(var + BN_EPS);
        const float av = gamma[ch] * rstd;
        a[ch]  = av;
        bb[ch] = beta[ch] - mean * av;
    }
}

// ---------------- fused: conv1 -> BN1+ELU -> conv2 -> (in-register) adjacency
//                  z = h2 @ L (bf16) -> ws, BN2 stats; h2 NEVER goes to memory.
__global__ __launch_bounds__(256, 2) void k_fused(
    const float* __restrict__ x, const __bf16* __restrict__ W1b, const __bf16* __restrict__ W2b,
    const __bf16* __restrict__ Ltb,
    const float* __restrict__ a1, const float* __restrict__ b1,
    __bf16* __restrict__ zws, float* __restrict__ sum2, float* __restrict__ sq2)
{
    __shared__ __bf16 wl[COUT_G * 72];            // 13824 B
    __shared__ __bf16 ht[4 * 6144];               // 49152 B: per-wave scratch (3 roles)
    __shared__ float a1l[96], b1l[96], st[192];
    const int b = blockIdx.z, g = blockIdx.y;
    for (int i = threadIdx.x; i < 768; i += 256) {
        const int idx = i * 8, o = idx >> 6, c = idx & 63;
        *(bf16x8*)&wl[o * 72 + c] = *(const bf16x8*)&W1b[g * 6144 + idx];
    }
    if (threadIdx.x < 96) {
        a1l[threadIdx.x] = a1[g * 96 + threadIdx.x];
        b1l[threadIdx.x] = b1[g * 96 + threadIdx.x];
    }
    if (threadIdx.x < 192) st[threadIdx.x] = 0.f;
    __syncthreads();

    const int wid = threadIdx.x >> 6, lane = threadIdx.x & 63;
    const int lg = lane >> 4, lr = lane & 15;
    const int jw = blockIdx.x * 4 + wid;          // wave's j row (0..255)
    const float* xb = x + ((size_t)b * CIN + g * CIN_G) * NPOS;
    char* htw = (char*)(ht + wid * 6144);         // 12288 B wave-private

    // ---- phase 1: C1[o][pos] = W1 @ x ; BN1+ELU ; k-packed LDS write (role 1: eh)
    {
        f32x4 acc1[6][4];
#pragma unroll
        for (int mt = 0; mt < 6; ++mt)
#pragma unroll
            for (int nt = 0; nt < 4; ++nt) acc1[mt][nt] = (f32x4){0.f,0.f,0.f,0.f};

#pragma unroll
        for (int ks = 0; ks < 2; ++ks) {
            const int c0 = ks * 32 + lg * 8;
            bf16x8 af[6];
#pragma unroll
            for (int mt = 0; mt < 6; ++mt)
                af[mt] = *(const bf16x8*)&wl[(mt * 16 + lr) * 72 + c0];
#pragma unroll
            for (int nt = 0; nt < 4; ++nt) {
                const int kcol = nt * 16 + lr;
                bf16x8 bfv;
                if (kcol < KDIM) {
                    const float* xp = xb + jw * KDIM + kcol;
#pragma unroll
                    for (int i = 0; i < 8; ++i) bfv[i] = (__bf16)xp[(size_t)(c0 + i) * NPOS];
                } else {
#pragma unroll
                    for (int i = 0; i < 8; ++i) bfv[i] = (__bf16)0.f;
                }
#pragma unroll
                for (int mt = 0; mt < 6; ++mt)
                    acc1[mt][nt] = __builtin_amdgcn_mfma_f32_16x16x32_bf16(af[mt], bfv, acc1[mt][nt], 0, 0, 0);
            }
        }
#pragma unroll
        for (int mt = 0; mt < 6; ++mt) {
            const int o0 = mt * 16 + lg * 4;
            const int c8 = o0 >> 3;
            const int half = (o0 & 7) >> 2;
#pragma unroll
            for (int nt = 0; nt < 4; ++nt) {
                const int pl = nt * 16 + lr;
                bf16x4 pv;
#pragma unroll
                for (int r = 0; r < 4; ++r) {
                    const int o = o0 + r;
                    float t = a1l[o] * acc1[mt][nt][r] + b1l[o];
                    t = t > 0.f ? t : (__expf(t) - 1.f);
                    pv[r] = (__bf16)t;
                }
                *(bf16x4*)(htw + c8 * 1024 + (pl ^ ((c8 & 3) << 1)) * 16 + half * 8) = pv;
            }
        }
    }

    // ---- phase 2: acc2[k-tile][ch-tile] = eh @ W2^T
    f32x4 acc2[4][6];
#pragma unroll
    for (int mt = 0; mt < 4; ++mt)
#pragma unroll
        for (int nt = 0; nt < 6; ++nt) acc2[mt][nt] = (f32x4){0.f,0.f,0.f,0.f};

#pragma unroll
    for (int ks = 0; ks < 3; ++ks) {
        const int c0 = ks * 32 + lg * 8;
        const int c8r = ks * 4 + lg;
        bf16x8 a2[4];
#pragma unroll
        for (int mt = 0; mt < 4; ++mt) {
            a2[mt] = *(const bf16x8*)(htw + c8r * 1024 + ((mt * 16 + lr) ^ ((c8r & 3) << 1)) * 16);
            if (mt == 3 && lr >= 14) {            // pad pos 62,63 -> zero rows
#pragma unroll
                for (int i = 0; i < 8; ++i) a2[mt][i] = (__bf16)0.f;
            }
        }
        bf16x8 bw[6];
#pragma unroll
        for (int nt = 0; nt < 6; ++nt)
            bw[nt] = *(const bf16x8*)&W2b[((size_t)g * 96 + nt * 16 + lr) * 96 + c0];
#pragma unroll
        for (int mt = 0; mt < 4; ++mt)
#pragma unroll
            for (int nt = 0; nt < 6; ++nt)
                acc2[mt][nt] = __builtin_amdgcn_mfma_f32_16x16x32_bf16(a2[mt], bw[nt], acc2[mt][nt], 0, 0, 0);
    }
    // acc2[mt][nt][r] = h2[ch = nt*16+lr][k = mt*16+lg*4+r]   (k=62,63 exact zero)

    // ---- BN2 stats (register-only, unchanged numerics)
#pragma unroll
    for (int nt = 0; nt < 6; ++nt) {
        const int o2 = nt * 16 + lr;
        float s = 0.f, q = 0.f;
#pragma unroll
        for (int mt = 0; mt < 4; ++mt)
#pragma unroll
            for (int r = 0; r < 4; ++r) {
                const float v = acc2[mt][nt][r];
                s += v; q += v * v;
            }
        s += __shfl_xor(s, 16); q += __shfl_xor(q, 16);
        s += __shfl_xor(s, 32); q += __shfl_xor(q, 32);
        if (lane < 16) {
            atomicAdd(&st[o2 * 2], s);
            atomicAdd(&st[o2 * 2 + 1], q);
        }
    }

    // ---- h2 -> wave-private LDS (role 2): k8-packed [k8][ch][8k] bf16
    // write: lanes stride 16B -> 2-way banks (free); read b128: same. No swizzle needed.
    __bf16* hz = (__bf16*)htw;
#pragma unroll
    for (int nt = 0; nt < 6; ++nt) {
#pragma unroll
        for (int mt = 0; mt < 4; ++mt) {
            bf16x4 pv;
#pragma unroll
            for (int r = 0; r < 4; ++r) pv[r] = (__bf16)acc2[mt][nt][r];
            const int k8 = mt * 2 + (lg >> 1);
            const int ch = nt * 16 + lr;
            *(bf16x4*)&hz[(k8 * 96 + ch) * 8 + (lg & 1) * 4] = pv;
        }
    }

    // ---- in-register adjacency: z[ch][p] = sum_k h2[ch][k] * Lt[p][k]
    f32x4 acc3[6][4];
#pragma unroll
    for (int ct = 0; ct < 6; ++ct)
#pragma unroll
        for (int pt = 0; pt < 4; ++pt) acc3[ct][pt] = (f32x4){0.f,0.f,0.f,0.f};

#pragma unroll
    for (int ks = 0; ks < 2; ++ks) {
        bf16x8 bl[4];
#pragma unroll
        for (int pt = 0; pt < 4; ++pt)
            bl[pt] = *(const bf16x8*)&Ltb[g * 4096 + (pt * 16 + lr) * 64 + ks * 32 + lg * 8];
#pragma unroll
        for (int ct = 0; ct < 6; ++ct) {
            const bf16x8 ah = *(const bf16x8*)&hz[((ks * 4 + lg) * 96 + ct * 16 + lr) * 8];
#pragma unroll
            for (int pt = 0; pt < 4; ++pt)
                acc3[ct][pt] = __builtin_amdgcn_mfma_f32_16x16x32_bf16(ah, bl[pt], acc3[ct][pt], 0, 0, 0);
        }
    }
    // acc3[ct][pt][r] = z[ch = ct*16+lg*4+r][p = pt*16+lr]

    // ---- z -> LDS (role 3: [ch][64p] bf16), then contiguous 12KB flush to ws
#pragma unroll
    for (int ct = 0; ct < 6; ++ct)
#pragma unroll
        for (int pt = 0; pt < 4; ++pt)
#pragma unroll
            for (int r = 0; r < 4; ++r)
                hz[(ct * 16 + lg * 4 + r) * 64 + pt * 16 + lr] = (__bf16)acc3[ct][pt][r];

    char* zg = (char*)(zws + ((size_t)((b * G + g) * 256 + jw)) * 6144);
#pragma unroll
    for (int it = 0; it < 12; ++it)
        *(f32x4*)(zg + it * 1024 + lane * 16) = *(const f32x4*)(htw + it * 1024 + lane * 16);

    __syncthreads();
    if (threadIdx.x < 96) {
        atomicAdd(&sum2[g * 96 + threadIdx.x], st[threadIdx.x * 2]);
        atomicAdd(&sq2[g * 96 + threadIdx.x], st[threadIdx.x * 2 + 1]);
    }
}

// ---------------- epilogue: y[b,ch,j,p] = a2[ch]*z[b,g,j,ch,p] + b2[ch]*colsum[p]
// reads z coalesced (12KB blocks), writes y as 248B-contiguous row segments
__global__ __launch_bounds__(256) void k_ep(
    const __bf16* __restrict__ zws, float* __restrict__ y,
    const float* __restrict__ a2, const float* __restrict__ b2,
    const float* __restrict__ lcs)
{
    __shared__ __bf16 zt[2 * 6144];    // 24576 B: two j-rows of z
    __shared__ float a2l[96], b2l[96];
    const int jc = blockIdx.x, g = blockIdx.y, b = blockIdx.z;
    const char* src = (const char*)(zws + ((size_t)((b * G + g) * 256 + jc * 2)) * 6144);
    for (int i = threadIdx.x; i < 1536; i += 256)
        *(f32x4*)((char*)zt + i * 16) = *(const f32x4*)(src + i * 16);
    if (threadIdx.x < 96) {
        a2l[threadIdx.x] = a2[g * 96 + threadIdx.x];
        b2l[threadIdx.x] = b2[g * 96 + threadIdx.x];
    }
    __syncthreads();

    const int wid = threadIdx.x >> 6, lane = threadIdx.x & 63;
    const float csv = lcs[g * 64 + (lane < KDIM ? lane : 0)];
#pragma unroll
    for (int jl = 0; jl < 2; ++jl) {
#pragma unroll
        for (int i = 0; i < 24; ++i) {
            const int ch = wid * 24 + i;
            const float zv = (float)zt[jl * 6144 + ch * 64 + lane];
            if (lane < KDIM)
                y[((size_t)(b * COUT + g * 96 + ch) * 256 + jc * 2 + jl) * KDIM + lane]
                    = a2l[ch] * zv + b2l[ch] * csv;
        }
    }
}

extern "C" void kernel_launch(void* const* d_in, const int* in_sizes, int n_in,
                              void* d_out, int out_size, void* d_ws, size_t ws_size,
                              hipStream_t stream)
{
    const float* x      = (const float*)d_in[0];
    const float* L      = (const float*)d_in[1];
    const float* W1     = (const float*)d_in[2];
    const float* W2     = (const float*)d_in[3];
    const float* gamma1 = (const float*)d_in[4];
    const float* beta1  = (const float*)d_in[5];
    const float* gamma2 = (const float*)d_in[6];
    const float* beta2  = (const float*)d_in[7];
    float* y = (float*)d_out;

    float* ws   = (float*)d_ws;
    float* sum1 = ws;            float* sq1 = ws + 480;
    float* sum2 = ws + 960;      float* sq2 = ws + 1440;
    float* a1   = ws + 1920;     float* b1  = ws + 2400;
    float* a2   = ws + 2880;     float* b2  = ws + 3360;
    float* lcs  = ws + 3840;     // 5*64 stride-64 padded
    __bf16* W1b = (__bf16*)(ws + 4160);   // 30720 bf16
    __bf16* W2b = (__bf16*)(ws + 19520);  // 46080 bf16
    __bf16* Ltb = (__bf16*)(ws + 42560);  // 20480 bf16
    __bf16* zws = (__bf16*)(ws + 52800);  // 8*5*256*6144 bf16 = 125.8 MB

    // zero sum1+sq1+sum2+sq2 (contiguous 1920 floats)
    hipMemsetAsync(ws, 0, 1920 * sizeof(float), stream);

    k_prep <<<305, 256, 0, stream>>>(W1, W2, L, W1b, W2b, Ltb, lcs);
    k_stat1<<<dim3(64, G, B), 256, 0, stream>>>(x, W1b, sum1, sq1);
    k_fin  <<<2, 256, 0, stream>>>(sum1, sq1, gamma1, beta1, a1, b1);
    k_fused<<<dim3(64, G, B), 256, 0, stream>>>(x, W1b, W2b, Ltb, a1, b1, zws, sum2, sq2);
    k_fin  <<<2, 256, 0, stream>>>(sum2, sq2, gamma2, beta2, a2, b2);
    k_ep   <<<dim3(128, G, B), 256, 0, stream>>>(zws, y, a2, b2, lcs);
}

// Round 18
// 250.622 us; speedup vs baseline: 1.0667x; 1.0667x over previous
//
#include <hip/hip_runtime.h>
#include <hip/hip_bf16.h>

#define G 5
#define B 8
#define CIN 320
#define CIN_G 64
#define COUT 480
#define COUT_G 96
#define NPOS 15872
#define NSTAT (B*NPOS)
#define BN_EPS 1e-5f
#define KDIM 62
#define SLABBF 31744        // bf16 slots per (b,ch) slab region of d_out

typedef float  f32x4 __attribute__((ext_vector_type(4)));
typedef float  f32x2 __attribute__((ext_vector_type(2)));
typedef __bf16 bf16x8 __attribute__((ext_vector_type(8)));
typedef __bf16 bf16x4 __attribute__((ext_vector_type(4)));

// ---------------- prep: W1,W2 -> bf16; L column sums (stride-64 padded for f32x4 reads)
__global__ __launch_bounds__(256) void k_prep(
    const float* __restrict__ W1, const float* __restrict__ W2, const float* __restrict__ L,
    __bf16* __restrict__ W1b, __bf16* __restrict__ W2b, float* __restrict__ lcs)
{
    const int bx = blockIdx.x;
    if (bx < 300) {
        const int i = bx * 256 + threadIdx.x;
        if (i < 30720) W1b[i] = (__bf16)W1[i];
        else W2b[i - 30720] = (__bf16)W2[i - 30720];
    } else {
        const int g = bx - 300, p = threadIdx.x;
        if (p < 64) {
            float s = 0.f;
            if (p < KDIM)
                for (int k = 0; k < KDIM; ++k) s += L[(g * KDIM + k) * KDIM + p];
            lcs[g * 64 + p] = s;
        }
    }
}

// ---------------- BN1 stats pass: conv1 to REGISTERS only (no h store), reduce stats.
__global__ __launch_bounds__(256) void k_stat1(
    const float* __restrict__ x, const __bf16* __restrict__ W1b,
    float* __restrict__ sum1, float* __restrict__ sq1)
{
    __shared__ __bf16 wl[COUT_G * 72];            // 13824 B
    __shared__ float st[COUT_G * 2];
    const int b = blockIdx.z, g = blockIdx.y;
    for (int i = threadIdx.x; i < 768; i += 256) {
        const int idx = i * 8, o = idx >> 6, c = idx & 63;
        *(bf16x8*)&wl[o * 72 + c] = *(const bf16x8*)&W1b[g * 6144 + idx];
    }
    if (threadIdx.x < COUT_G * 2) st[threadIdx.x] = 0.f;
    __syncthreads();

    const int wid = threadIdx.x >> 6, lane = threadIdx.x & 63;
    const int lg = lane >> 4, lr = lane & 15;
    const int jw = blockIdx.x * 4 + wid;          // wave's j row (0..255)
    const float* xb = x + ((size_t)b * CIN + g * CIN_G) * NPOS;

    f32x4 acc1[6][4];
#pragma unroll
    for (int mt = 0; mt < 6; ++mt)
#pragma unroll
        for (int nt = 0; nt < 4; ++nt) acc1[mt][nt] = (f32x4){0.f,0.f,0.f,0.f};

#pragma unroll
    for (int ks = 0; ks < 2; ++ks) {
        const int c0 = ks * 32 + lg * 8;
        bf16x8 af[6];
#pragma unroll
        for (int mt = 0; mt < 6; ++mt)
            af[mt] = *(const bf16x8*)&wl[(mt * 16 + lr) * 72 + c0];
#pragma unroll
        for (int nt = 0; nt < 4; ++nt) {
            const int kcol = nt * 16 + lr;
            bf16x8 bfv;
            if (kcol < KDIM) {
                const float* xp = xb + jw * KDIM + kcol;
#pragma unroll
                for (int i = 0; i < 8; ++i) bfv[i] = (__bf16)xp[(size_t)(c0 + i) * NPOS];
            } else {
#pragma unroll
                for (int i = 0; i < 8; ++i) bfv[i] = (__bf16)0.f;
            }
#pragma unroll
            for (int mt = 0; mt < 6; ++mt)
                acc1[mt][nt] = __builtin_amdgcn_mfma_f32_16x16x32_bf16(af[mt], bfv, acc1[mt][nt], 0, 0, 0);
        }
    }

    // stats: channel o = mt*16+lg*4+r, summed over nt and lr (pad cols are exact 0)
#pragma unroll
    for (int mt = 0; mt < 6; ++mt) {
#pragma unroll
        for (int r = 0; r < 4; ++r) {
            float s = 0.f, q = 0.f;
#pragma unroll
            for (int nt = 0; nt < 4; ++nt) {
                const float v = acc1[mt][nt][r];
                s += v; q += v * v;
            }
#pragma unroll
            for (int m = 1; m <= 8; m <<= 1) {
                s += __shfl_xor(s, m);
                q += __shfl_xor(q, m);
            }
            if (lr == 0) {
                atomicAdd(&st[(mt * 16 + lg * 4 + r) * 2], s);
                atomicAdd(&st[(mt * 16 + lg * 4 + r) * 2 + 1], q);
            }
        }
    }
    __syncthreads();
    if (threadIdx.x < COUT_G) {
        atomicAdd(&sum1[g * COUT_G + threadIdx.x], st[threadIdx.x * 2]);
        atomicAdd(&sq1[g * COUT_G + threadIdx.x], st[threadIdx.x * 2 + 1]);
    }
}

// ---------------- BN coefs (shared by BN1 and BN2)
__global__ void k_fin(const float* __restrict__ sum, const float* __restrict__ sq,
                      const float* __restrict__ gamma, const float* __restrict__ beta,
                      float* __restrict__ a, float* __restrict__ bb)
{
    const int ch = blockIdx.x * blockDim.x + threadIdx.x;
    if (ch < COUT) {
        const float invN = 1.f / (float)NSTAT;
        const float mean = sum[ch] * invN;
        const float var  = sq[ch] * invN - mean * mean;
        const float rstd = rsqrtf(var + BN_EPS);
        const float av = gamma[ch] * rstd;
        a[ch]  = av;
        bb[ch] = beta[ch] - mean * av;
    }
}

// ---------------- fused: recompute h=W1@x, BN1+ELU, conv2 -> h2 bf16 (in d_out); BN2 stats
// (exact R11/R16 configuration -- best measured)
__global__ __launch_bounds__(256, 2) void k_fused(
    const float* __restrict__ x, const __bf16* __restrict__ W1b, const __bf16* __restrict__ W2b,
    const float* __restrict__ a1, const float* __restrict__ b1,
    __bf16* __restrict__ h2b, float* __restrict__ sum2, float* __restrict__ sq2)
{
    __shared__ __bf16 wl[COUT_G * 72];            // 13824 B
    __shared__ __bf16 ht[4 * 6144];               // 49152 B: per-wave k-packed h tiles
    __shared__ float a1l[96], b1l[96], st[192];
    const int b = blockIdx.z, g = blockIdx.y;
    for (int i = threadIdx.x; i < 768; i += 256) {
        const int idx = i * 8, o = idx >> 6, c = idx & 63;
        *(bf16x8*)&wl[o * 72 + c] = *(const bf16x8*)&W1b[g * 6144 + idx];
    }
    if (threadIdx.x < 96) {
        a1l[threadIdx.x] = a1[g * 96 + threadIdx.x];
        b1l[threadIdx.x] = b1[g * 96 + threadIdx.x];
    }
    if (threadIdx.x < 192) st[threadIdx.x] = 0.f;
    __syncthreads();

    const int wid = threadIdx.x >> 6, lane = threadIdx.x & 63;
    const int lg = lane >> 4, lr = lane & 15;
    const int jw = blockIdx.x * 4 + wid;          // wave's j row (0..255)
    const float* xb = x + ((size_t)b * CIN + g * CIN_G) * NPOS;
    char* htw = (char*)(ht + wid * 6144);

    // ---- phase 1: C1[o][pos] = W1 @ x ; BN1+ELU ; swizzled k-packed LDS write
    {
        f32x4 acc1[6][4];
#pragma unroll
        for (int mt = 0; mt < 6; ++mt)
#pragma unroll
            for (int nt = 0; nt < 4; ++nt) acc1[mt][nt] = (f32x4){0.f,0.f,0.f,0.f};

#pragma unroll
        for (int ks = 0; ks < 2; ++ks) {
            const int c0 = ks * 32 + lg * 8;
            bf16x8 af[6];
#pragma unroll
            for (int mt = 0; mt < 6; ++mt)
                af[mt] = *(const bf16x8*)&wl[(mt * 16 + lr) * 72 + c0];
#pragma unroll
            for (int nt = 0; nt < 4; ++nt) {
                const int kcol = nt * 16 + lr;
                bf16x8 bfv;
                if (kcol < KDIM) {
                    const float* xp = xb + jw * KDIM + kcol;
#pragma unroll
                    for (int i = 0; i < 8; ++i) bfv[i] = (__bf16)xp[(size_t)(c0 + i) * NPOS];
                } else {
#pragma unroll
                    for (int i = 0; i < 8; ++i) bfv[i] = (__bf16)0.f;
                }
#pragma unroll
                for (int mt = 0; mt < 6; ++mt)
                    acc1[mt][nt] = __builtin_amdgcn_mfma_f32_16x16x32_bf16(af[mt], bfv, acc1[mt][nt], 0, 0, 0);
            }
        }
#pragma unroll
        for (int mt = 0; mt < 6; ++mt) {
            const int o0 = mt * 16 + lg * 4;
            const int c8 = o0 >> 3;
            const int half = (o0 & 7) >> 2;
#pragma unroll
            for (int nt = 0; nt < 4; ++nt) {
                const int pl = nt * 16 + lr;
                bf16x4 pv;
#pragma unroll
                for (int r = 0; r < 4; ++r) {
                    const int o = o0 + r;
                    float t = a1l[o] * acc1[mt][nt][r] + b1l[o];
                    t = t > 0.f ? t : (__expf(t) - 1.f);
                    pv[r] = (__bf16)t;
                }
                *(bf16x4*)(htw + c8 * 1024 + (pl ^ ((c8 & 3) << 1)) * 16 + half * 8) = pv;
            }
        }
    }

    // ---- phase 2: acc2[pos][ch] = eh @ W2^T
    f32x4 acc2[4][6];
#pragma unroll
    for (int mt = 0; mt < 4; ++mt)
#pragma unroll
        for (int nt = 0; nt < 6; ++nt) acc2[mt][nt] = (f32x4){0.f,0.f,0.f,0.f};

#pragma unroll
    for (int ks = 0; ks < 3; ++ks) {
        const int c0 = ks * 32 + lg * 8;
        const int c8r = ks * 4 + lg;
        bf16x8 a2[4];
#pragma unroll
        for (int mt = 0; mt < 4; ++mt) {
            a2[mt] = *(const bf16x8*)(htw + c8r * 1024 + ((mt * 16 + lr) ^ ((c8r & 3) << 1)) * 16);
            if (mt == 3 && lr >= 14) {            // pad pos 62,63 -> zero rows
#pragma unroll
                for (int i = 0; i < 8; ++i) a2[mt][i] = (__bf16)0.f;
            }
        }
        bf16x8 bw[6];
#pragma unroll
        for (int nt = 0; nt < 6; ++nt)
            bw[nt] = *(const bf16x8*)&W2b[((size_t)g * 96 + nt * 16 + lr) * 96 + c0];
#pragma unroll
        for (int mt = 0; mt < 4; ++mt)
#pragma unroll
            for (int nt = 0; nt < 6; ++nt)
                acc2[mt][nt] = __builtin_amdgcn_mfma_f32_16x16x32_bf16(a2[mt], bw[nt], acc2[mt][nt], 0, 0, 0);
    }

    // store h2 bf16 (sparse in d_out) + BN2 stats
#pragma unroll
    for (int nt = 0; nt < 6; ++nt) {
        const int o2 = nt * 16 + lr;
        __bf16* sb = h2b + ((size_t)b * COUT + g * 96 + o2) * SLABBF + (size_t)jw * 64;
        float s = 0.f, q = 0.f;
#pragma unroll
        for (int mt = 0; mt < 4; ++mt) {
            bf16x4 pv;
#pragma unroll
            for (int r = 0; r < 4; ++r) {
                const float v = acc2[mt][nt][r];
                s += v; q += v * v;
                pv[r] = (__bf16)v;
            }
            *(bf16x4*)&sb[mt * 16 + lg * 4] = pv;
        }
        s += __shfl_xor(s, 16); q += __shfl_xor(q, 16);
        s += __shfl_xor(s, 32); q += __shfl_xor(q, 32);
        if (lane < 16) {
            atomicAdd(&st[o2 * 2], s);
            atomicAdd(&st[o2 * 2 + 1], q);
        }
    }
    __syncthreads();
    if (threadIdx.x < 96) {
        atomicAdd(&sum2[g * 96 + threadIdx.x], st[threadIdx.x * 2]);
        atomicAdd(&sq2[g * 96 + threadIdx.x], st[threadIdx.x * 2 + 1]);
    }
}

// ---------------- adjacency (MFMA, A=L^T, B=h2^T -> C[p][j]); in-place on d_out
// CHANGE vs R16: y-flush vectorized to f32x4 (1KB/instr; was dword 256B/instr)
__global__ __launch_bounds__(256) void k_adj(
    float* __restrict__ y, const float* __restrict__ L,
    const float* __restrict__ a2, const float* __restrict__ b2,
    const float* __restrict__ lcs)
{
    __shared__ __bf16 Lt[64 * 72];       // 9216 B: Lt[p][k], zero-padded
    __shared__ float yt[4][32 * KDIM];   // 31744 B: per-wave 32x62 f32 y half-tile
    const int ch = blockIdx.x, b = blockIdx.y;
    const int g = ch / COUT_G;
    const int s = b * COUT + ch;
    const float* Lg = L + g * KDIM * KDIM;
    const __bf16* h2b = (const __bf16*)y;

    for (int i = threadIdx.x; i < 4096; i += 256) {
        const int p = i >> 6, k = i & 63;
        Lt[p * 72 + k] = (__bf16)((p < KDIM && k < KDIM) ? Lg[k * KDIM + p] : 0.f);
    }

    const int wid = threadIdx.x >> 6, lane = threadIdx.x & 63;
    const int lg = lane >> 4, lr = lane & 15;
    const int j0 = wid * 64;

    // stage ALL h2 B-frags before the barrier (barrier drains vmcnt -> safe in-place)
    bf16x8 bt[4][2];
#pragma unroll
    for (int nt = 0; nt < 4; ++nt)
#pragma unroll
        for (int ks = 0; ks < 2; ++ks)
            bt[nt][ks] = *(const bf16x8*)&h2b[(size_t)s * SLABBF + (j0 + nt * 16 + lr) * 64 + ks * 32 + lg * 8];
    __syncthreads();

    bf16x8 lt[4][2];
#pragma unroll
    for (int mt = 0; mt < 4; ++mt)
#pragma unroll
        for (int ks = 0; ks < 2; ++ks)
            lt[mt][ks] = *(const bf16x8*)&Lt[(mt * 16 + lr) * 72 + ks * 32 + lg * 8];

    f32x4 acc[4][4];
#pragma unroll
    for (int mt = 0; mt < 4; ++mt)
#pragma unroll
        for (int nt = 0; nt < 4; ++nt) acc[mt][nt] = (f32x4){0.f,0.f,0.f,0.f};

#pragma unroll
    for (int ks = 0; ks < 2; ++ks)
#pragma unroll
        for (int nt = 0; nt < 4; ++nt)
#pragma unroll
            for (int mt = 0; mt < 4; ++mt)
                acc[mt][nt] = __builtin_amdgcn_mfma_f32_16x16x32_bf16(lt[mt][ks], bt[nt][ks], acc[mt][nt], 0, 0, 0);

    const float av = a2[ch], bv = b2[ch];
    f32x4 lcv[4];
#pragma unroll
    for (int mt = 0; mt < 4; ++mt)
        lcv[mt] = *(const f32x4*)&lcs[g * 64 + mt * 16 + lg * 4];   // 16B-aligned (stride-64 pad)

    float* ytw = yt[wid];
    // two halves: compute 32 rows into LDS, flush as contiguous 1KB/instr f32x4 stream.
    // wave-private region -> no barriers; per-wave LDS ordering handles the roundtrip.
#pragma unroll
    for (int half = 0; half < 2; ++half) {
#pragma unroll
        for (int nth = 0; nth < 2; ++nth) {
            const int nt = half * 2 + nth;
            const int row = nth * 16 + lr;       // 0..31 within half
#pragma unroll
            for (int mt = 0; mt < 4; ++mt) {
                const int p0 = mt * 16 + lg * 4;
                f32x2 v0 = { av * acc[mt][nt][0] + bv * lcv[mt][0],
                             av * acc[mt][nt][1] + bv * lcv[mt][1] };
                *(f32x2*)&ytw[row * KDIM + p0] = v0;
                if (p0 < 60) {
                    f32x2 v1 = { av * acc[mt][nt][2] + bv * lcv[mt][2],
                                 av * acc[mt][nt][3] + bv * lcv[mt][3] };
                    *(f32x2*)&ytw[row * KDIM + p0 + 2] = v1;
                }
            }
        }
        // flush 32*62 = 1984 dwords = 496 f32x4 chunks; 8 iters x 64 lanes (last partial)
        float* yg = y + (size_t)s * NPOS + (j0 + half * 32) * KDIM;
#pragma unroll
        for (int it = 0; it < 8; ++it) {
            const int idx = it * 64 + lane;
            if (idx < 496)
                *(f32x4*)&yg[idx * 4] = *(const f32x4*)&ytw[idx * 4];
        }
    }
}

extern "C" void kernel_launch(void* const* d_in, const int* in_sizes, int n_in,
                              void* d_out, int out_size, void* d_ws, size_t ws_size,
                              hipStream_t stream)
{
    const float* x      = (const float*)d_in[0];
    const float* L      = (const float*)d_in[1];
    const float* W1     = (const float*)d_in[2];
    const float* W2     = (const float*)d_in[3];
    const float* gamma1 = (const float*)d_in[4];
    const float* beta1  = (const float*)d_in[5];
    const float* gamma2 = (const float*)d_in[6];
    const float* beta2  = (const float*)d_in[7];
    float* y = (float*)d_out;

    float* ws   = (float*)d_ws;
    float* sum1 = ws;            float* sq1 = ws + 480;
    float* sum2 = ws + 960;      float* sq2 = ws + 1440;
    float* a1   = ws + 1920;     float* b1  = ws + 2400;
    float* a2   = ws + 2880;     float* b2  = ws + 3360;
    float* lcs  = ws + 3840;     // 5*64 = 320 (stride-64 padded)
    __bf16* W1b = (__bf16*)(ws + 4160);   // 30720 bf16
    __bf16* W2b = (__bf16*)(ws + 19520);  // 46080 bf16

    // zero sum1+sq1+sum2+sq2 (contiguous 1920 floats)
    hipMemsetAsync(ws, 0, 1920 * sizeof(float), stream);

    k_prep <<<305, 256, 0, stream>>>(W1, W2, L, W1b, W2b, lcs);
    k_stat1<<<dim3(64, G, B), 256, 0, stream>>>(x, W1b, sum1, sq1);
    k_fin  <<<2, 256, 0, stream>>>(sum1, sq1, gamma1, beta1, a1, b1);
    k_fused<<<dim3(64, G, B), 256, 0, stream>>>(x, W1b, W2b, a1, b1, (__bf16*)d_out, sum2, sq2);
    k_fin  <<<2, 256, 0, stream>>>(sum2, sq2, gamma2, beta2, a2, b2);
    k_adj  <<<dim3(COUT, B), 256, 0, stream>>>(y, L, a2, b2, lcs);
}

// Round 19
// 240.061 us; speedup vs baseline: 1.1136x; 1.0440x over previous
//
#include <hip/hip_runtime.h>
#include <hip/hip_bf16.h>

#define G 5
#define B 8
#define CIN 320
#define CIN_G 64
#define COUT 480
#define COUT_G 96
#define NPOS 15872
#define NSTAT (B*NPOS)
#define BN_EPS 1e-5f
#define KDIM 62
#define SLABBF 31744        // bf16 slots per (b,ch) slab region of d_out

typedef float  f32x4 __attribute__((ext_vector_type(4)));
typedef float  f32x2 __attribute__((ext_vector_type(2)));
typedef __bf16 bf16x8 __attribute__((ext_vector_type(8)));
typedef __bf16 bf16x4 __attribute__((ext_vector_type(4)));

// ---------------- prep: W1,W2 -> bf16; Ltb[g][p][64k] transposed bf16 zero-padded;
//                  L column sums (stride-64 padded)
__global__ __launch_bounds__(256) void k_prep(
    const float* __restrict__ W1, const float* __restrict__ W2, const float* __restrict__ L,
    __bf16* __restrict__ W1b, __bf16* __restrict__ W2b, __bf16* __restrict__ Ltb,
    float* __restrict__ lcs)
{
    const int bx = blockIdx.x;
    if (bx < 300) {
        const int i = bx * 256 + threadIdx.x;
        if (i < 30720) W1b[i] = (__bf16)W1[i];
        else W2b[i - 30720] = (__bf16)W2[i - 30720];
    } else {
        const int g = bx - 300;
        for (int e = threadIdx.x; e < 4096; e += 256) {
            const int p = e >> 6, k = e & 63;
            Ltb[g * 4096 + e] = (__bf16)((p < KDIM && k < KDIM) ? L[(g * KDIM + k) * KDIM + p] : 0.f);
        }
        if (threadIdx.x < 64) {
            float s = 0.f;
            if (threadIdx.x < KDIM)
                for (int k = 0; k < KDIM; ++k) s += L[(g * KDIM + k) * KDIM + threadIdx.x];
            lcs[g * 64 + threadIdx.x] = s;
        }
    }
}

// ---------------- BN1 stats pass: conv1 to REGISTERS only (no h store), reduce stats.
__global__ __launch_bounds__(256) void k_stat1(
    const float* __restrict__ x, const __bf16* __restrict__ W1b,
    float* __restrict__ sum1, float* __restrict__ sq1)
{
    __shared__ __bf16 wl[COUT_G * 72];            // 13824 B
    __shared__ float st[COUT_G * 2];
    const int b = blockIdx.z, g = blockIdx.y;
    for (int i = threadIdx.x; i < 768; i += 256) {
        const int idx = i * 8, o = idx >> 6, c = idx & 63;
        *(bf16x8*)&wl[o * 72 + c] = *(const bf16x8*)&W1b[g * 6144 + idx];
    }
    if (threadIdx.x < COUT_G * 2) st[threadIdx.x] = 0.f;
    __syncthreads();

    const int wid = threadIdx.x >> 6, lane = threadIdx.x & 63;
    const int lg = lane >> 4, lr = lane & 15;
    const int jw = blockIdx.x * 4 + wid;          // wave's j row (0..255)
    const float* xb = x + ((size_t)b * CIN + g * CIN_G) * NPOS;

    f32x4 acc1[6][4];
#pragma unroll
    for (int mt = 0; mt < 6; ++mt)
#pragma unroll
        for (int nt = 0; nt < 4; ++nt) acc1[mt][nt] = (f32x4){0.f,0.f,0.f,0.f};

#pragma unroll
    for (int ks = 0; ks < 2; ++ks) {
        const int c0 = ks * 32 + lg * 8;
        bf16x8 af[6];
#pragma unroll
        for (int mt = 0; mt < 6; ++mt)
            af[mt] = *(const bf16x8*)&wl[(mt * 16 + lr) * 72 + c0];
#pragma unroll
        for (int nt = 0; nt < 4; ++nt) {
            const int kcol = nt * 16 + lr;
            bf16x8 bfv;
            if (kcol < KDIM) {
                const float* xp = xb + jw * KDIM + kcol;
#pragma unroll
                for (int i = 0; i < 8; ++i) bfv[i] = (__bf16)xp[(size_t)(c0 + i) * NPOS];
            } else {
#pragma unroll
                for (int i = 0; i < 8; ++i) bfv[i] = (__bf16)0.f;
            }
#pragma unroll
            for (int mt = 0; mt < 6; ++mt)
                acc1[mt][nt] = __builtin_amdgcn_mfma_f32_16x16x32_bf16(af[mt], bfv, acc1[mt][nt], 0, 0, 0);
        }
    }

    // stats: channel o = mt*16+lg*4+r, summed over nt and lr (pad cols are exact 0)
#pragma unroll
    for (int mt = 0; mt < 6; ++mt) {
#pragma unroll
        for (int r = 0; r < 4; ++r) {
            float s = 0.f, q = 0.f;
#pragma unroll
            for (int nt = 0; nt < 4; ++nt) {
                const float v = acc1[mt][nt][r];
                s += v; q += v * v;
            }
#pragma unroll
            for (int m = 1; m <= 8; m <<= 1) {
                s += __shfl_xor(s, m);
                q += __shfl_xor(q, m);
            }
            if (lr == 0) {
                atomicAdd(&st[(mt * 16 + lg * 4 + r) * 2], s);
                atomicAdd(&st[(mt * 16 + lg * 4 + r) * 2 + 1], q);
            }
        }
    }
    __syncthreads();
    if (threadIdx.x < COUT_G) {
        atomicAdd(&sum1[g * COUT_G + threadIdx.x], st[threadIdx.x * 2]);
        atomicAdd(&sq1[g * COUT_G + threadIdx.x], st[threadIdx.x * 2 + 1]);
    }
}

// ---------------- fused: recompute h=W1@x, BN1+ELU, conv2 -> h2 bf16 (in d_out); BN2 stats
// CHANGE vs R18: BN1 coefs computed in-preamble from sum1/sq1 (k_fin folded in)
__global__ __launch_bounds__(256, 2) void k_fused(
    const float* __restrict__ x, const __bf16* __restrict__ W1b, const __bf16* __restrict__ W2b,
    const float* __restrict__ sum1, const float* __restrict__ sq1,
    const float* __restrict__ gamma1, const float* __restrict__ beta1,
    __bf16* __restrict__ h2b, float* __restrict__ sum2, float* __restrict__ sq2)
{
    __shared__ __bf16 wl[COUT_G * 72];            // 13824 B
    __shared__ __bf16 ht[4 * 6144];               // 49152 B: per-wave k-packed h tiles
    __shared__ float a1l[96], b1l[96], st[192];
    const int b = blockIdx.z, g = blockIdx.y;
    for (int i = threadIdx.x; i < 768; i += 256) {
        const int idx = i * 8, o = idx >> 6, c = idx & 63;
        *(bf16x8*)&wl[o * 72 + c] = *(const bf16x8*)&W1b[g * 6144 + idx];
    }
    if (threadIdx.x < 96) {
        const int ch = g * 96 + threadIdx.x;
        const float invN = 1.f / (float)NSTAT;
        const float mean = sum1[ch] * invN;
        const float var  = sq1[ch] * invN - mean * mean;
        const float av = gamma1[ch] * rsqrtf(var + BN_EPS);
        a1l[threadIdx.x] = av;
        b1l[threadIdx.x] = beta1[ch] - mean * av;
    }
    if (threadIdx.x < 192) st[threadIdx.x] = 0.f;
    __syncthreads();

    const int wid = threadIdx.x >> 6, lane = threadIdx.x & 63;
    const int lg = lane >> 4, lr = lane & 15;
    const int jw = blockIdx.x * 4 + wid;          // wave's j row (0..255)
    const float* xb = x + ((size_t)b * CIN + g * CIN_G) * NPOS;
    char* htw = (char*)(ht + wid * 6144);

    // ---- phase 1: C1[o][pos] = W1 @ x ; BN1+ELU ; swizzled k-packed LDS write
    {
        f32x4 acc1[6][4];
#pragma unroll
        for (int mt = 0; mt < 6; ++mt)
#pragma unroll
            for (int nt = 0; nt < 4; ++nt) acc1[mt][nt] = (f32x4){0.f,0.f,0.f,0.f};

#pragma unroll
        for (int ks = 0; ks < 2; ++ks) {
            const int c0 = ks * 32 + lg * 8;
            bf16x8 af[6];
#pragma unroll
            for (int mt = 0; mt < 6; ++mt)
                af[mt] = *(const bf16x8*)&wl[(mt * 16 + lr) * 72 + c0];
#pragma unroll
            for (int nt = 0; nt < 4; ++nt) {
                const int kcol = nt * 16 + lr;
                bf16x8 bfv;
                if (kcol < KDIM) {
                    const float* xp = xb + jw * KDIM + kcol;
#pragma unroll
                    for (int i = 0; i < 8; ++i) bfv[i] = (__bf16)xp[(size_t)(c0 + i) * NPOS];
                } else {
#pragma unroll
                    for (int i = 0; i < 8; ++i) bfv[i] = (__bf16)0.f;
                }
#pragma unroll
                for (int mt = 0; mt < 6; ++mt)
                    acc1[mt][nt] = __builtin_amdgcn_mfma_f32_16x16x32_bf16(af[mt], bfv, acc1[mt][nt], 0, 0, 0);
            }
        }
#pragma unroll
        for (int mt = 0; mt < 6; ++mt) {
            const int o0 = mt * 16 + lg * 4;
            const int c8 = o0 >> 3;
            const int half = (o0 & 7) >> 2;
#pragma unroll
            for (int nt = 0; nt < 4; ++nt) {
                const int pl = nt * 16 + lr;
                bf16x4 pv;
#pragma unroll
                for (int r = 0; r < 4; ++r) {
                    const int o = o0 + r;
                    float t = a1l[o] * acc1[mt][nt][r] + b1l[o];
                    t = t > 0.f ? t : (__expf(t) - 1.f);
                    pv[r] = (__bf16)t;
                }
                *(bf16x4*)(htw + c8 * 1024 + (pl ^ ((c8 & 3) << 1)) * 16 + half * 8) = pv;
            }
        }
    }

    // ---- phase 2: acc2[pos][ch] = eh @ W2^T
    f32x4 acc2[4][6];
#pragma unroll
    for (int mt = 0; mt < 4; ++mt)
#pragma unroll
        for (int nt = 0; nt < 6; ++nt) acc2[mt][nt] = (f32x4){0.f,0.f,0.f,0.f};

#pragma unroll
    for (int ks = 0; ks < 3; ++ks) {
        const int c0 = ks * 32 + lg * 8;
        const int c8r = ks * 4 + lg;
        bf16x8 a2[4];
#pragma unroll
        for (int mt = 0; mt < 4; ++mt) {
            a2[mt] = *(const bf16x8*)(htw + c8r * 1024 + ((mt * 16 + lr) ^ ((c8r & 3) << 1)) * 16);
            if (mt == 3 && lr >= 14) {            // pad pos 62,63 -> zero rows
#pragma unroll
                for (int i = 0; i < 8; ++i) a2[mt][i] = (__bf16)0.f;
            }
        }
        bf16x8 bw[6];
#pragma unroll
        for (int nt = 0; nt < 6; ++nt)
            bw[nt] = *(const bf16x8*)&W2b[((size_t)g * 96 + nt * 16 + lr) * 96 + c0];
#pragma unroll
        for (int mt = 0; mt < 4; ++mt)
#pragma unroll
            for (int nt = 0; nt < 6; ++nt)
                acc2[mt][nt] = __builtin_amdgcn_mfma_f32_16x16x32_bf16(a2[mt], bw[nt], acc2[mt][nt], 0, 0, 0);
    }

    // store h2 bf16 (sparse in d_out) + BN2 stats
#pragma unroll
    for (int nt = 0; nt < 6; ++nt) {
        const int o2 = nt * 16 + lr;
        __bf16* sb = h2b + ((size_t)b * COUT + g * 96 + o2) * SLABBF + (size_t)jw * 64;
        float s = 0.f, q = 0.f;
#pragma unroll
        for (int mt = 0; mt < 4; ++mt) {
            bf16x4 pv;
#pragma unroll
            for (int r = 0; r < 4; ++r) {
                const float v = acc2[mt][nt][r];
                s += v; q += v * v;
                pv[r] = (__bf16)v;
            }
            *(bf16x4*)&sb[mt * 16 + lg * 4] = pv;
        }
        s += __shfl_xor(s, 16); q += __shfl_xor(q, 16);
        s += __shfl_xor(s, 32); q += __shfl_xor(q, 32);
        if (lane < 16) {
            atomicAdd(&st[o2 * 2], s);
            atomicAdd(&st[o2 * 2 + 1], q);
        }
    }
    __syncthreads();
    if (threadIdx.x < 96) {
        atomicAdd(&sum2[g * 96 + threadIdx.x], st[threadIdx.x * 2]);
        atomicAdd(&sq2[g * 96 + threadIdx.x], st[threadIdx.x * 2 + 1]);
    }
}

// ---------------- adjacency (MFMA, A=L^T, B=h2^T -> C[p][j]); in-place on d_out
// CHANGE vs R18: Lt LDS staging removed (lt frags from prepped L2-hot Ltb global);
//                BN2 coefs computed inline (k_fin folded in)
__global__ __launch_bounds__(256) void k_adj(
    float* __restrict__ y, const __bf16* __restrict__ Ltb,
    const float* __restrict__ sum2, const float* __restrict__ sq2,
    const float* __restrict__ gamma2, const float* __restrict__ beta2,
    const float* __restrict__ lcs)
{
    __shared__ float yt[4][32 * KDIM];   // 31744 B: per-wave 32x62 f32 y half-tile
    const int ch = blockIdx.x, b = blockIdx.y;
    const int g = ch / COUT_G;
    const int s = b * COUT + ch;
    const __bf16* h2b = (const __bf16*)y;

    const int wid = threadIdx.x >> 6, lane = threadIdx.x & 63;
    const int lg = lane >> 4, lr = lane & 15;
    const int j0 = wid * 64;

    // stage ALL h2 B-frags before the barrier (barrier drains vmcnt -> safe in-place)
    bf16x8 bt[4][2];
#pragma unroll
    for (int nt = 0; nt < 4; ++nt)
#pragma unroll
        for (int ks = 0; ks < 2; ++ks)
            bt[nt][ks] = *(const bf16x8*)&h2b[(size_t)s * SLABBF + (j0 + nt * 16 + lr) * 64 + ks * 32 + lg * 8];

    bf16x8 lt[4][2];
#pragma unroll
    for (int mt = 0; mt < 4; ++mt)
#pragma unroll
        for (int ks = 0; ks < 2; ++ks)
            lt[mt][ks] = *(const bf16x8*)&Ltb[g * 4096 + (mt * 16 + lr) * 64 + ks * 32 + lg * 8];

    // BN2 coefs inline (uniform per block; scalar loads)
    const float invN = 1.f / (float)NSTAT;
    const float mean = sum2[ch] * invN;
    const float var  = sq2[ch] * invN - mean * mean;
    const float av = gamma2[ch] * rsqrtf(var + BN_EPS);
    const float bv = beta2[ch] - mean * av;

    __syncthreads();   // all waves' h2 reads complete before any y store below

    f32x4 acc[4][4];
#pragma unroll
    for (int mt = 0; mt < 4; ++mt)
#pragma unroll
        for (int nt = 0; nt < 4; ++nt) acc[mt][nt] = (f32x4){0.f,0.f,0.f,0.f};

#pragma unroll
    for (int ks = 0; ks < 2; ++ks)
#pragma unroll
        for (int nt = 0; nt < 4; ++nt)
#pragma unroll
            for (int mt = 0; mt < 4; ++mt)
                acc[mt][nt] = __builtin_amdgcn_mfma_f32_16x16x32_bf16(lt[mt][ks], bt[nt][ks], acc[mt][nt], 0, 0, 0);

    f32x4 lcv[4];
#pragma unroll
    for (int mt = 0; mt < 4; ++mt)
        lcv[mt] = *(const f32x4*)&lcs[g * 64 + mt * 16 + lg * 4];   // 16B-aligned (stride-64 pad)

    float* ytw = yt[wid];
    // two halves: compute 32 rows into LDS, flush as contiguous 1KB/instr f32x4 stream.
#pragma unroll
    for (int half = 0; half < 2; ++half) {
#pragma unroll
        for (int nth = 0; nth < 2; ++nth) {
            const int nt = half * 2 + nth;
            const int row = nth * 16 + lr;       // 0..31 within half
#pragma unroll
            for (int mt = 0; mt < 4; ++mt) {
                const int p0 = mt * 16 + lg * 4;
                f32x2 v0 = { av * acc[mt][nt][0] + bv * lcv[mt][0],
                             av * acc[mt][nt][1] + bv * lcv[mt][1] };
                *(f32x2*)&ytw[row * KDIM + p0] = v0;
                if (p0 < 60) {
                    f32x2 v1 = { av * acc[mt][nt][2] + bv * lcv[mt][2],
                                 av * acc[mt][nt][3] + bv * lcv[mt][3] };
                    *(f32x2*)&ytw[row * KDIM + p0 + 2] = v1;
                }
            }
        }
        // flush 32*62 = 1984 dwords = 496 f32x4 chunks; 8 iters x 64 lanes (last partial)
        float* yg = y + (size_t)s * NPOS + (j0 + half * 32) * KDIM;
#pragma unroll
        for (int it = 0; it < 8; ++it) {
            const int idx = it * 64 + lane;
            if (idx < 496)
                *(f32x4*)&yg[idx * 4] = *(const f32x4*)&ytw[idx * 4];
        }
    }
}

extern "C" void kernel_launch(void* const* d_in, const int* in_sizes, int n_in,
                              void* d_out, int out_size, void* d_ws, size_t ws_size,
                              hipStream_t stream)
{
    const float* x      = (const float*)d_in[0];
    const float* L      = (const float*)d_in[1];
    const float* W1     = (const float*)d_in[2];
    const float* W2     = (const float*)d_in[3];
    const float* gamma1 = (const float*)d_in[4];
    const float* beta1  = (const float*)d_in[5];
    const float* gamma2 = (const float*)d_in[6];
    const float* beta2  = (const float*)d_in[7];
    float* y = (float*)d_out;

    float* ws   = (float*)d_ws;
    float* sum1 = ws;            float* sq1 = ws + 480;
    float* sum2 = ws + 960;      float* sq2 = ws + 1440;
    float* lcs  = ws + 1920;     // 5*64 = 320 (stride-64 padded)
    __bf16* W1b = (__bf16*)(ws + 2240);   // 30720 bf16
    __bf16* W2b = (__bf16*)(ws + 17600);  // 46080 bf16
    __bf16* Ltb = (__bf16*)(ws + 40640);  // 20480 bf16

    // zero sum1+sq1+sum2+sq2 (contiguous 1920 floats)
    hipMemsetAsync(ws, 0, 1920 * sizeof(float), stream);

    k_prep <<<305, 256, 0, stream>>>(W1, W2, L, W1b, W2b, Ltb, lcs);
    k_stat1<<<dim3(64, G, B), 256, 0, stream>>>(x, W1b, sum1, sq1);
    k_fused<<<dim3(64, G, B), 256, 0, stream>>>(x, W1b, W2b, sum1, sq1, gamma1, beta1,
                                                (__bf16*)d_out, sum2, sq2);
    k_adj  <<<dim3(COUT, B), 256, 0, stream>>>(y, Ltb, sum2, sq2, gamma2, beta2, lcs);
}